// Round 3
// baseline (2099.656 us; speedup 1.0000x reference)
//
#include <hip/hip_runtime.h>

#define DEV __device__ __forceinline__

typedef __bf16 bf16x8 __attribute__((ext_vector_type(8)));
typedef float f32x4 __attribute__((ext_vector_type(4)));
typedef unsigned short ushort8 __attribute__((ext_vector_type(8)));

constexpr int BATCH = 8192;
constexpr int HD    = 2048;   // per-gate width = per-source K

DEV float bf2f(unsigned short u) {
    unsigned int v = (unsigned int)u << 16;
    return __builtin_bit_cast(float, v);
}
DEV unsigned short f2bf(float f) {
    unsigned int v = __builtin_bit_cast(unsigned int, f);
    unsigned int r = (v + 0x7FFFu + ((v >> 16) & 1u)) >> 16;  // RNE
    return (unsigned short)r;
}
DEV float sigm(float v)  { return 1.0f / (1.0f + __expf(-v)); }
DEV float tanh_(float v) {
    float z = fminf(fmaxf(v, -15.0f), 15.0f);
    float e = __expf(2.0f * z);
    return (e - 1.0f) / (e + 1.0f);
}
// scalar load of logical element i, under either storage dtype
DEV float ldany(const void* p, size_t i, int is_f32) {
    return is_f32 ? ((const float*)p)[i] : bf2f(((const unsigned short*)p)[i]);
}

// ---------------- dtype sniffer -------------------------------------------
// bf16 N(0,1) storage: ushort exponent fields land in [100,129], never 0xFF.
// f32 storage: every even ushort is low-mantissa bits (uniform) -> ~40% have
// exponent <100. Count weird exponents over the first 2048 ushorts (4 KB,
// in-bounds under both interpretations).
__global__ void sniff_dtype(const unsigned short* __restrict__ x, int* __restrict__ flag) {
    __shared__ int cnt;
    if (threadIdx.x == 0) cnt = 0;
    __syncthreads();
    int local = 0;
#pragma unroll
    for (int j = 0; j < 8; ++j) {
        unsigned short u = x[threadIdx.x * 8 + j];
        int e = (u >> 7) & 0xFF;
        if (e < 100 || e == 0xFF) ++local;
    }
    atomicAdd(&cnt, local);
    __syncthreads();
    if (threadIdx.x == 0) flag[0] = (cnt > 64) ? 1 : 0;   // 1 => f32 storage
}

// ---------------- fused LSTM: 2 GEMMs + gates ------------------------------
// Block tile: 64 batch rows x 128 gate-cols x 3 gates, BK=32.
// Staging: register load (dtype-adaptive, convert to bf16) + ds_write_b128.
DEV void stage64(unsigned short* lds, const void* src, int is_f32,
                 size_t row_base, int kk, int tid) {
    const int r  = tid >> 2;          // 0..63
    const int cc = (tid & 3) * 8;     // 0,8,16,24
    ushort8 v;
    if (is_f32) {
        const float* s = (const float*)src + (row_base + r) * (size_t)HD + kk + cc;
        f32x4 u0 = *(const f32x4*)s;
        f32x4 u1 = *(const f32x4*)(s + 4);
#pragma unroll
        for (int j = 0; j < 4; ++j) { v[j] = f2bf(u0[j]); v[4 + j] = f2bf(u1[j]); }
    } else {
        v = *(const ushort8*)((const unsigned short*)src + (row_base + r) * (size_t)HD + kk + cc);
    }
    *reinterpret_cast<ushort8*>(&lds[r * 32 + cc]) = v;
}

__global__ __launch_bounds__(256, 2) void lstm_fused(
    const void* __restrict__ x,   const void* __restrict__ h,
    const void* __restrict__ c,
    const void* __restrict__ Wix, const void* __restrict__ bix,
    const void* __restrict__ Wmx, const void* __restrict__ bmx,
    const void* __restrict__ Wox, const void* __restrict__ box_,
    const void* __restrict__ Wih, const void* __restrict__ bih,
    const void* __restrict__ Wmh, const void* __restrict__ bmh,
    const void* __restrict__ Woh, const void* __restrict__ boh,
    void* __restrict__ out, const int* __restrict__ flag)
{
    __shared__ unsigned short As[64 * 32];
    __shared__ unsigned short B0s[128 * 32];
    __shared__ unsigned short B1s[128 * 32];
    __shared__ unsigned short B2s[128 * 32];

    const int is_f32 = flag[0];

    const int tid  = threadIdx.x;
    const int lane = tid & 63;
    const int wave = tid >> 6;

    const int n0 = blockIdx.x * 128;   // gate-col tile
    const int m0 = blockIdx.y * 64;    // batch tile

    // compute geometry: wave quadrant 32(M) x 64(N)
    const int mOff = (wave >> 1) * 32;
    const int nOff = (wave & 1) * 64;
    const int q    = lane >> 4;
    const int ml   = lane & 15;

    f32x4 a0[2][4] = {};   // gate i
    f32x4 a1[2][4] = {};   // gate m
    f32x4 a2[2][4] = {};   // gate o

    auto kstep = [&](const void* Asrc, const void* W0, const void* W1,
                     const void* W2, int kk) {
        stage64(As, Asrc, is_f32, m0, kk, tid);
        stage64(B0s,          W0, is_f32, n0,      kk, tid);
        stage64(B0s + 64 * 32, W0, is_f32, n0 + 64, kk, tid);
        stage64(B1s,          W1, is_f32, n0,      kk, tid);
        stage64(B1s + 64 * 32, W1, is_f32, n0 + 64, kk, tid);
        stage64(B2s,          W2, is_f32, n0,      kk, tid);
        stage64(B2s + 64 * 32, W2, is_f32, n0 + 64, kk, tid);
        __syncthreads();

        bf16x8 af[2], bfr[4];
        af[0] = *reinterpret_cast<const bf16x8*>(&As[(mOff      + ml) * 32 + q * 8]);
        af[1] = *reinterpret_cast<const bf16x8*>(&As[(mOff + 16 + ml) * 32 + q * 8]);

#pragma unroll
        for (int tn = 0; tn < 4; ++tn)
            bfr[tn] = *reinterpret_cast<const bf16x8*>(&B0s[(nOff + tn * 16 + ml) * 32 + q * 8]);
#pragma unroll
        for (int tm = 0; tm < 2; ++tm)
#pragma unroll
            for (int tn = 0; tn < 4; ++tn)
                a0[tm][tn] = __builtin_amdgcn_mfma_f32_16x16x32_bf16(af[tm], bfr[tn], a0[tm][tn], 0, 0, 0);

#pragma unroll
        for (int tn = 0; tn < 4; ++tn)
            bfr[tn] = *reinterpret_cast<const bf16x8*>(&B1s[(nOff + tn * 16 + ml) * 32 + q * 8]);
#pragma unroll
        for (int tm = 0; tm < 2; ++tm)
#pragma unroll
            for (int tn = 0; tn < 4; ++tn)
                a1[tm][tn] = __builtin_amdgcn_mfma_f32_16x16x32_bf16(af[tm], bfr[tn], a1[tm][tn], 0, 0, 0);

#pragma unroll
        for (int tn = 0; tn < 4; ++tn)
            bfr[tn] = *reinterpret_cast<const bf16x8*>(&B2s[(nOff + tn * 16 + ml) * 32 + q * 8]);
#pragma unroll
        for (int tm = 0; tm < 2; ++tm)
#pragma unroll
            for (int tn = 0; tn < 4; ++tn)
                a2[tm][tn] = __builtin_amdgcn_mfma_f32_16x16x32_bf16(af[tm], bfr[tn], a2[tm][tn], 0, 0, 0);

        __syncthreads();
    };

    for (int kt = 0; kt < 64; ++kt)          // x @ Wx^T half
        kstep(x, Wix, Wmx, Wox, kt * 32);
    for (int kt = 0; kt < 64; ++kt)          // h @ Wh^T half
        kstep(h, Wih, Wmh, Woh, kt * 32);

    // ---- fused LSTM epilogue; C/D map: col = lane&15, row = (lane>>4)*4+reg
#pragma unroll
    for (int tn = 0; tn < 4; ++tn) {
        const int col = n0 + nOff + tn * 16 + ml;          // 0..2047
        const float Bi = ldany(bix, col, is_f32) + ldany(bih, col, is_f32);
        const float Bm = ldany(bmx, col, is_f32) + ldany(bmh, col, is_f32);
        const float Bo = ldany(box_, col, is_f32) + ldany(boh, col, is_f32);
#pragma unroll
        for (int tm = 0; tm < 2; ++tm) {
            const int rb = m0 + mOff + tm * 16 + q * 4;
#pragma unroll
            for (int r = 0; r < 4; ++r) {
                const size_t b = rb + r;
                const float cold = ldany(c, b * HD + col, is_f32);
                const float gi = a0[tm][tn][r] + Bi;
                const float gm = a1[tm][tn][r] + Bm;
                const float go = a2[tm][tn][r] + Bo;
                const float i_s = sigm(gi);
                const float f_s = sigm(gm);    // reference quirk: gm drives both
                const float m_s = tanh_(gm);   // forget-sigmoid and candidate-tanh
                const float o_s = sigm(go);
                const float cn  = f_s * cold + i_s * m_s;
                const float hn  = o_s * tanh_(cn);
                if (is_f32) {
                    float* ho = (float*)out;
                    float* co = ho + (size_t)BATCH * HD;
                    ho[b * HD + col] = hn;
                    co[b * HD + col] = cn;
                } else {
                    unsigned short* ho = (unsigned short*)out;
                    unsigned short* co = ho + (size_t)BATCH * HD;
                    ho[b * HD + col] = f2bf(hn);
                    co[b * HD + col] = f2bf(cn);
                }
            }
        }
    }
}

// ----------------------------------------------------------------------------
extern "C" void kernel_launch(void* const* d_in, const int* in_sizes, int n_in,
                              void* d_out, int out_size, void* d_ws, size_t ws_size,
                              hipStream_t stream) {
    const void* x   = d_in[0];
    const void* h   = d_in[1];
    const void* c   = d_in[2];
    const void* Wix = d_in[3];  const void* bix = d_in[4];
    const void* Wmx = d_in[5];  const void* bmx = d_in[6];
    const void* Wox = d_in[7];  const void* box_= d_in[8];
    const void* Wih = d_in[9];  const void* bih = d_in[10];
    const void* Wmh = d_in[11]; const void* bmh = d_in[12];
    const void* Woh = d_in[13]; const void* boh = d_in[14];

    int* flag = (int*)d_ws;

    sniff_dtype<<<dim3(1), dim3(256), 0, stream>>>(
        (const unsigned short*)x, flag);

    lstm_fused<<<dim3(HD / 128, BATCH / 64), dim3(256), 0, stream>>>(
        x, h, c, Wix, bix, Wmx, bmx, Wox, box_,
        Wih, bih, Wmh, bmh, Woh, boh, d_out, flag);
}

// Round 4
// 798.135 us; speedup vs baseline: 2.6307x; 2.6307x over previous
//
#include <hip/hip_runtime.h>

#define DEV __device__ __forceinline__

typedef __bf16 bf16x8 __attribute__((ext_vector_type(8)));
typedef float f32x4 __attribute__((ext_vector_type(4)));
typedef unsigned short ushort8 __attribute__((ext_vector_type(8)));

constexpr int BATCH = 8192;
constexpr int HD    = 2048;                    // per-gate width = per-source K
constexpr size_t NX   = (size_t)BATCH * HD;    // x / h element count
constexpr size_t NW   = (size_t)HD * HD;       // one weight matrix
constexpr size_t NTOT = 2 * NX + 6 * NW;       // 58,720,256 elements

DEV unsigned short f2bf(float f) {
    unsigned int v = __builtin_bit_cast(unsigned int, f);
    unsigned int r = (v + 0x7FFFu + ((v >> 16) & 1u)) >> 16;  // RNE
    return (unsigned short)r;
}
DEV float sigm(float v)  { return 1.0f / (1.0f + __expf(-v)); }
DEV float tanh_(float v) {
    float z = fminf(fmaxf(v, -15.0f), 15.0f);
    float e = __expf(2.0f * z);
    return (e - 1.0f) / (e + 1.0f);
}

// async 16B/lane global->LDS; LDS base wave-uniform, lane l lands at base+l*16.
DEV void gl16(const unsigned short* g, unsigned short* lds_uniform_base) {
    __builtin_amdgcn_global_load_lds(
        (const __attribute__((address_space(1))) unsigned int*)g,
        (__attribute__((address_space(3))) unsigned int*)lds_uniform_base,
        16, 0, 0);
}

// ---------------- phase 1: f32 -> bf16 conversion into d_ws ----------------
// Layout in ws (ushort): [ x | h | Wix | Wmx | Wox | Wih | Wmh | Woh ]
struct CvtArgs { const float* src[8]; };

__global__ __launch_bounds__(256) void cvt_all(CvtArgs a, unsigned short* __restrict__ dst) {
    const size_t starts[9] = {0, NX, 2*NX, 2*NX+NW, 2*NX+2*NW, 2*NX+3*NW,
                              2*NX+4*NW, 2*NX+5*NW, NTOT};
    const size_t base = (size_t)blockIdx.x * 2048;   // all seg bounds % 2048 == 0
    int s = 0;
    while (base >= starts[s + 1]) ++s;
    const float* src = a.src[s] + (base - starts[s]) + threadIdx.x * 8;
    f32x4 u0 = *reinterpret_cast<const f32x4*>(src);
    f32x4 u1 = *reinterpret_cast<const f32x4*>(src + 4);
    ushort8 v;
#pragma unroll
    for (int j = 0; j < 4; ++j) { v[j] = f2bf(u0[j]); v[4 + j] = f2bf(u1[j]); }
    *reinterpret_cast<ushort8*>(dst + base + threadIdx.x * 8) = v;
}

// ---------------- phase 2: fused 3-gate GEMM + LSTM epilogue ---------------
// Block tile: 128 batch x 128 gate-cols x 3 gates, BK=32, 4 waves.
// Per wave: 64x64 quadrant per gate -> 48 MFMA : 16 ds_read_b128 per kstep.
__global__ __launch_bounds__(256, 2) void lstm_fast(
    const unsigned short* __restrict__ xb, const unsigned short* __restrict__ hb,
    const unsigned short* __restrict__ W0x, const unsigned short* __restrict__ W1x,
    const unsigned short* __restrict__ W2x, const unsigned short* __restrict__ W0h,
    const unsigned short* __restrict__ W1h, const unsigned short* __restrict__ W2h,
    const float* __restrict__ c,
    const float* __restrict__ bix, const float* __restrict__ bih,
    const float* __restrict__ bmx, const float* __restrict__ bmh,
    const float* __restrict__ box_, const float* __restrict__ boh,
    float* __restrict__ hout, float* __restrict__ cout)
{
    __shared__ unsigned short As [128 * 32];
    __shared__ unsigned short B0s[128 * 32];
    __shared__ unsigned short B1s[128 * 32];
    __shared__ unsigned short B2s[128 * 32];

    const int tid  = threadIdx.x;
    const int lane = tid & 63;
    const int wave = tid >> 6;

    const int n0 = blockIdx.x * 128;   // gate-col tile (0..15)
    const int m0 = blockIdx.y * 128;   // batch tile   (0..63)

    const int arow = lane >> 2;        // staging: 16 rows / gl16
    const int acol = (lane & 3) * 8;   // 4 lanes/row, 16B each

    const int mOff = (wave >> 1) * 64;
    const int nOff = (wave & 1) * 64;
    const int q    = lane >> 4;
    const int ml   = lane & 15;

    f32x4 a0[4][4] = {};   // gate i
    f32x4 a1[4][4] = {};   // gate m
    f32x4 a2[4][4] = {};   // gate o

    const int r0 = wave * 32, r1 = wave * 32 + 16;

    for (int kt = 0; kt < 128; ++kt) {
        const int k0 = kt * 32;
        const unsigned short *Asrc, *W0, *W1, *W2;
        int kk;
        if (k0 < HD) { Asrc = xb; W0 = W0x; W1 = W1x; W2 = W2x; kk = k0; }
        else         { Asrc = hb; W0 = W0h; W1 = W1h; W2 = W2h; kk = k0 - HD; }

        gl16(Asrc + (size_t)(m0 + r0 + arow) * HD + kk + acol, &As [r0 * 32]);
        gl16(Asrc + (size_t)(m0 + r1 + arow) * HD + kk + acol, &As [r1 * 32]);
        gl16(W0   + (size_t)(n0 + r0 + arow) * HD + kk + acol, &B0s[r0 * 32]);
        gl16(W0   + (size_t)(n0 + r1 + arow) * HD + kk + acol, &B0s[r1 * 32]);
        gl16(W1   + (size_t)(n0 + r0 + arow) * HD + kk + acol, &B1s[r0 * 32]);
        gl16(W1   + (size_t)(n0 + r1 + arow) * HD + kk + acol, &B1s[r1 * 32]);
        gl16(W2   + (size_t)(n0 + r0 + arow) * HD + kk + acol, &B2s[r0 * 32]);
        gl16(W2   + (size_t)(n0 + r1 + arow) * HD + kk + acol, &B2s[r1 * 32]);
        __syncthreads();

        bf16x8 af[4];
#pragma unroll
        for (int t = 0; t < 4; ++t)
            af[t] = *reinterpret_cast<const bf16x8*>(&As[(mOff + t * 16 + ml) * 32 + q * 8]);

        {
            bf16x8 bfr[4];
#pragma unroll
            for (int tn = 0; tn < 4; ++tn)
                bfr[tn] = *reinterpret_cast<const bf16x8*>(&B0s[(nOff + tn * 16 + ml) * 32 + q * 8]);
#pragma unroll
            for (int tm = 0; tm < 4; ++tm)
#pragma unroll
                for (int tn = 0; tn < 4; ++tn)
                    a0[tm][tn] = __builtin_amdgcn_mfma_f32_16x16x32_bf16(af[tm], bfr[tn], a0[tm][tn], 0, 0, 0);
        }
        {
            bf16x8 bfr[4];
#pragma unroll
            for (int tn = 0; tn < 4; ++tn)
                bfr[tn] = *reinterpret_cast<const bf16x8*>(&B1s[(nOff + tn * 16 + ml) * 32 + q * 8]);
#pragma unroll
            for (int tm = 0; tm < 4; ++tm)
#pragma unroll
                for (int tn = 0; tn < 4; ++tn)
                    a1[tm][tn] = __builtin_amdgcn_mfma_f32_16x16x32_bf16(af[tm], bfr[tn], a1[tm][tn], 0, 0, 0);
        }
        {
            bf16x8 bfr[4];
#pragma unroll
            for (int tn = 0; tn < 4; ++tn)
                bfr[tn] = *reinterpret_cast<const bf16x8*>(&B2s[(nOff + tn * 16 + ml) * 32 + q * 8]);
#pragma unroll
            for (int tm = 0; tm < 4; ++tm)
#pragma unroll
                for (int tn = 0; tn < 4; ++tn)
                    a2[tm][tn] = __builtin_amdgcn_mfma_f32_16x16x32_bf16(af[tm], bfr[tn], a2[tm][tn], 0, 0, 0);
        }
        __syncthreads();
    }

    // LSTM epilogue; C/D map (m89-verified): col = lane&15, row = (lane>>4)*4+reg
#pragma unroll
    for (int tn = 0; tn < 4; ++tn) {
        const int col = n0 + nOff + tn * 16 + ml;      // 0..2047
        const float Bi = bix[col] + bih[col];
        const float Bm = bmx[col] + bmh[col];
        const float Bo = box_[col] + boh[col];
#pragma unroll
        for (int tm = 0; tm < 4; ++tm) {
            const int rb = m0 + mOff + tm * 16 + q * 4;
#pragma unroll
            for (int r = 0; r < 4; ++r) {
                const size_t b = rb + r;
                const float cold = c[b * HD + col];
                const float gi = a0[tm][tn][r] + Bi;
                const float gm = a1[tm][tn][r] + Bm;
                const float go = a2[tm][tn][r] + Bo;
                const float i_s = sigm(gi);
                const float f_s = sigm(gm);    // reference quirk: gm drives both
                const float m_s = tanh_(gm);   // forget-sigmoid and candidate-tanh
                const float o_s = sigm(go);
                const float cn  = f_s * cold + i_s * m_s;
                const float hn  = o_s * tanh_(cn);
                hout[b * HD + col] = hn;
                cout[b * HD + col] = cn;
            }
        }
    }
}

// ---------------- fallback (R3-proven, f32 in, no ws) ----------------------
DEV void stage64f(unsigned short* lds, const float* src, size_t row_base, int kk, int tid) {
    const int r  = tid >> 2;
    const int cc = (tid & 3) * 8;
    const float* s = src + (row_base + r) * (size_t)HD + kk + cc;
    f32x4 u0 = *(const f32x4*)s;
    f32x4 u1 = *(const f32x4*)(s + 4);
    ushort8 v;
#pragma unroll
    for (int j = 0; j < 4; ++j) { v[j] = f2bf(u0[j]); v[4 + j] = f2bf(u1[j]); }
    *reinterpret_cast<ushort8*>(&lds[r * 32 + cc]) = v;
}

__global__ __launch_bounds__(256, 2) void lstm_slow(
    const float* __restrict__ x,   const float* __restrict__ h,
    const float* __restrict__ c,
    const float* __restrict__ Wix, const float* __restrict__ bix,
    const float* __restrict__ Wmx, const float* __restrict__ bmx,
    const float* __restrict__ Wox, const float* __restrict__ box_,
    const float* __restrict__ Wih, const float* __restrict__ bih,
    const float* __restrict__ Wmh, const float* __restrict__ bmh,
    const float* __restrict__ Woh, const float* __restrict__ boh,
    float* __restrict__ hout, float* __restrict__ cout)
{
    __shared__ unsigned short As[64 * 32];
    __shared__ unsigned short B0s[128 * 32];
    __shared__ unsigned short B1s[128 * 32];
    __shared__ unsigned short B2s[128 * 32];

    const int tid  = threadIdx.x;
    const int lane = tid & 63;
    const int wave = tid >> 6;
    const int n0 = blockIdx.x * 128;
    const int m0 = blockIdx.y * 64;
    const int mOff = (wave >> 1) * 32;
    const int nOff = (wave & 1) * 64;
    const int q    = lane >> 4;
    const int ml   = lane & 15;

    f32x4 a0[2][4] = {}; f32x4 a1[2][4] = {}; f32x4 a2[2][4] = {};

    auto kstep = [&](const float* Asrc, const float* W0, const float* W1,
                     const float* W2, int kk) {
        stage64f(As, Asrc, m0, kk, tid & 255);
        stage64f(B0s,           W0, n0,      kk, tid);
        stage64f(B0s + 64 * 32, W0, n0 + 64, kk, tid);
        stage64f(B1s,           W1, n0,      kk, tid);
        stage64f(B1s + 64 * 32, W1, n0 + 64, kk, tid);
        stage64f(B2s,           W2, n0,      kk, tid);
        stage64f(B2s + 64 * 32, W2, n0 + 64, kk, tid);
        __syncthreads();
        bf16x8 af[2], bfr[4];
        af[0] = *reinterpret_cast<const bf16x8*>(&As[(mOff      + ml) * 32 + q * 8]);
        af[1] = *reinterpret_cast<const bf16x8*>(&As[(mOff + 16 + ml) * 32 + q * 8]);
#pragma unroll
        for (int tn = 0; tn < 4; ++tn)
            bfr[tn] = *reinterpret_cast<const bf16x8*>(&B0s[(nOff + tn * 16 + ml) * 32 + q * 8]);
#pragma unroll
        for (int tm = 0; tm < 2; ++tm)
#pragma unroll
            for (int tn = 0; tn < 4; ++tn)
                a0[tm][tn] = __builtin_amdgcn_mfma_f32_16x16x32_bf16(af[tm], bfr[tn], a0[tm][tn], 0, 0, 0);
#pragma unroll
        for (int tn = 0; tn < 4; ++tn)
            bfr[tn] = *reinterpret_cast<const bf16x8*>(&B1s[(nOff + tn * 16 + ml) * 32 + q * 8]);
#pragma unroll
        for (int tm = 0; tm < 2; ++tm)
#pragma unroll
            for (int tn = 0; tn < 4; ++tn)
                a1[tm][tn] = __builtin_amdgcn_mfma_f32_16x16x32_bf16(af[tm], bfr[tn], a1[tm][tn], 0, 0, 0);
#pragma unroll
        for (int tn = 0; tn < 4; ++tn)
            bfr[tn] = *reinterpret_cast<const bf16x8*>(&B2s[(nOff + tn * 16 + ml) * 32 + q * 8]);
#pragma unroll
        for (int tm = 0; tm < 2; ++tm)
#pragma unroll
            for (int tn = 0; tn < 4; ++tn)
                a2[tm][tn] = __builtin_amdgcn_mfma_f32_16x16x32_bf16(af[tm], bfr[tn], a2[tm][tn], 0, 0, 0);
        __syncthreads();
    };

    for (int kt = 0; kt < 64; ++kt) kstep(x, Wix, Wmx, Wox, kt * 32);
    for (int kt = 0; kt < 64; ++kt) kstep(h, Wih, Wmh, Woh, kt * 32);

#pragma unroll
    for (int tn = 0; tn < 4; ++tn) {
        const int col = n0 + nOff + tn * 16 + ml;
        const float Bi = bix[col] + bih[col];
        const float Bm = bmx[col] + bmh[col];
        const float Bo = box_[col] + boh[col];
#pragma unroll
        for (int tm = 0; tm < 2; ++tm) {
            const int rb = m0 + mOff + tm * 16 + q * 4;
#pragma unroll
            for (int r = 0; r < 4; ++r) {
                const size_t b = rb + r;
                const float cold = c[b * HD + col];
                const float gi = a0[tm][tn][r] + Bi;
                const float gm = a1[tm][tn][r] + Bm;
                const float go = a2[tm][tn][r] + Bo;
                const float cn = sigm(gm) * cold + sigm(gi) * tanh_(gm);
                const float hn = sigm(go) * tanh_(cn);
                hout[b * HD + col] = hn;
                cout[b * HD + col] = cn;
            }
        }
    }
}

// ----------------------------------------------------------------------------
extern "C" void kernel_launch(void* const* d_in, const int* in_sizes, int n_in,
                              void* d_out, int out_size, void* d_ws, size_t ws_size,
                              hipStream_t stream) {
    const float* x   = (const float*)d_in[0];
    const float* h   = (const float*)d_in[1];
    const float* c   = (const float*)d_in[2];
    const float* Wix = (const float*)d_in[3];  const float* bix = (const float*)d_in[4];
    const float* Wmx = (const float*)d_in[5];  const float* bmx = (const float*)d_in[6];
    const float* Wox = (const float*)d_in[7];  const float* box_= (const float*)d_in[8];
    const float* Wih = (const float*)d_in[9];  const float* bih = (const float*)d_in[10];
    const float* Wmh = (const float*)d_in[11]; const float* bmh = (const float*)d_in[12];
    const float* Woh = (const float*)d_in[13]; const float* boh = (const float*)d_in[14];

    float* hout = (float*)d_out;
    float* cout = hout + NX;

    if (ws_size >= NTOT * sizeof(unsigned short)) {
        unsigned short* ws = (unsigned short*)d_ws;
        CvtArgs a;
        a.src[0] = x;   a.src[1] = h;
        a.src[2] = Wix; a.src[3] = Wmx; a.src[4] = Wox;
        a.src[5] = Wih; a.src[6] = Wmh; a.src[7] = Woh;
        cvt_all<<<dim3((unsigned)(NTOT / 2048)), dim3(256), 0, stream>>>(a, ws);

        const unsigned short* xb  = ws;
        const unsigned short* hb  = ws + NX;
        const unsigned short* W0x = ws + 2 * NX;           // Wix
        const unsigned short* W1x = ws + 2 * NX + NW;      // Wmx
        const unsigned short* W2x = ws + 2 * NX + 2 * NW;  // Wox
        const unsigned short* W0h = ws + 2 * NX + 3 * NW;  // Wih
        const unsigned short* W1h = ws + 2 * NX + 4 * NW;  // Wmh
        const unsigned short* W2h = ws + 2 * NX + 5 * NW;  // Woh

        lstm_fast<<<dim3(HD / 128, BATCH / 128), dim3(256), 0, stream>>>(
            xb, hb, W0x, W1x, W2x, W0h, W1h, W2h,
            c, bix, bih, bmx, bmh, box_, boh, hout, cout);
    } else {
        lstm_slow<<<dim3(HD / 128, BATCH / 64), dim3(256), 0, stream>>>(
            x, h, c, Wix, bix, Wmx, bmx, Wox, box_,
            Wih, bih, Wmh, bmh, Woh, boh, hout, cout);
    }
}